// Round 18
// baseline (309.649 us; speedup 1.0000x reference)
//
#include <hip/hip_runtime.h>
#include <hip/hip_bf16.h>

// MoE FFN: T=4096 tokens, D=1024, E=8, H=1408, top-2.
// R18: R17 (174.7us) + combine fused into gemm2 via last-writer
// threadfence-reduction: per (token, nt-column-block) u32 counter (zeroed in
// build_lists); each gemm2 block after storing its contrib tile fences and
// atomically increments the counters of its rows; the SECOND arriver combines
// that row (contrib[2t]+contrib[2t+1] -> f32 out). Two slots of a token are
// always different experts -> different blocks -> counter reaches exactly 2;
// value-deterministic (add computed once). R17's tail-fill (wd transpose in
// gemm1 grid) kept.

#define T_TOK 4096
#define D_DIM 1024
#define E_NUM 8
#define H_DIM 1408

typedef __bf16 bf16_t;
typedef __bf16 bf16x8 __attribute__((ext_vector_type(8)));
typedef float f32x4 __attribute__((ext_vector_type(4)));

// ---- workspace layout (bytes) ----
#define OFF_COUNTS   0
#define OFF_COMB     256                                   // T*E*4 = 131072
#define OFF_LISTS    (OFF_COMB + T_TOK*E_NUM*4)            // E*T*4 = 131072
#define OFF_PAIRS    (OFF_LISTS + E_NUM*T_TOK*4)           // T bytes
#define OFF_XBF      (OFF_PAIRS + T_TOK)                   // T*D*2
#define OFF_WGT      (OFF_XBF + (size_t)T_TOK*D_DIM*2)     // E*H*D*2 each
#define OFF_WUT      (OFF_WGT + (size_t)E_NUM*H_DIM*D_DIM*2)
#define OFF_WDT      (OFF_WUT + (size_t)E_NUM*H_DIM*D_DIM*2)
#define OFF_H        (OFF_WDT + (size_t)E_NUM*H_DIM*D_DIM*2)
#define OFF_CONTRIB  (OFF_H + (size_t)2*T_TOK*H_DIM*2)
#define OFF_CTR      (OFF_CONTRIB + (size_t)2*T_TOK*D_DIM*2)  // T*8*4 = 131072
// total ~117.9 MB

#define NTRANS_BLOCKS 5632   // wg + wu only (wd transpose moved to gemm1 grid)
#define NROUTER_BLOCKS (T_TOK / 4)
#define NG1_BLOCKS (E_NUM * (T_TOK / 128) * (H_DIM / 128))  // 2816
#define NWD_BLOCKS 2816       // (D/64) x (H/64) x E

__device__ __forceinline__ void gload16(const bf16_t* g, bf16_t* l) {
    __builtin_amdgcn_global_load_lds(
        (const __attribute__((address_space(1))) void*)g,
        (__attribute__((address_space(3))) void*)l,
        16, 0, 0);
}

// Shared transpose body: in [R][C] fp32 tile (rt,ct) of expert e -> out [C][R] bf16.
__device__ __forceinline__ void transpose_tile(
    const float* __restrict__ in, bf16_t* __restrict__ out, int R, int C,
    int e, int rt, int ct, int tid, bf16_t (*tile)[65])
{
    int r = tid >> 2, c0 = (tid & 3) * 16;
    const float* src = in + ((size_t)e * R + rt * 64) * C + (size_t)ct * 64;
#pragma unroll
    for (int q = 0; q < 4; ++q) {
        float4 f = *(const float4*)(src + (size_t)r * C + c0 + q * 4);
        tile[c0 + q * 4 + 0][r] = (bf16_t)f.x;
        tile[c0 + q * 4 + 1][r] = (bf16_t)f.y;
        tile[c0 + q * 4 + 2][r] = (bf16_t)f.z;
        tile[c0 + q * 4 + 3][r] = (bf16_t)f.w;
    }
    __syncthreads();
    bf16_t* dst = out + ((size_t)e * C + ct * 64) * R + (size_t)rt * 64;
    int cc = tid >> 2, rr0 = (tid & 3) * 16;
    bf16x8 v0, v1;
#pragma unroll
    for (int q = 0; q < 8; ++q) { v0[q] = tile[cc][rr0 + q]; v1[q] = tile[cc][rr0 + 8 + q]; }
    *(bf16x8*)(dst + (size_t)cc * R + rr0) = v0;
    *(bf16x8*)(dst + (size_t)cc * R + rr0 + 8) = v1;
}

// Fused pre-pass: wg/wu transpose+convert (blocks [0,5632)) + router (rest).
__global__ __launch_bounds__(256) void prep_kernel(
    const float* __restrict__ wg, const float* __restrict__ wu,
    bf16_t* __restrict__ wgT, bf16_t* __restrict__ wuT,
    const float* __restrict__ x, const float* __restrict__ wr,
    bf16_t* __restrict__ xbf, float* __restrict__ comb,
    unsigned char* __restrict__ pairs)
{
    int bid = blockIdx.x;
    int tid = threadIdx.x;

    if (bid < NTRANS_BLOCKS) {
        __shared__ bf16_t tile[64][65];
        const float* in; bf16_t* out;
        if (bid < 2816)      { in = wg; out = wgT; }
        else                 { in = wu; out = wuT; bid -= 2816; }
        int nct = H_DIM / 64;            // 22
        int ct = bid % nct;
        int rt = (bid / nct) % (D_DIM / 64);
        int e  = bid / (nct * (D_DIM / 64));
        transpose_tile(in, out, D_DIM, H_DIM, e, rt, ct, tid, tile);
        return;
    }

    // ---- router ----
    int widx = tid >> 6;
    int lane = tid & 63;
    int t = (bid - NTRANS_BLOCKS) * 4 + widx;
    const float* xr = x + (size_t)t * D_DIM;

    {
        const float4* xv4 = (const float4*)(xr + lane * 16);
        bf16_t* xbr = xbf + (size_t)t * D_DIM + lane * 16;
        float4 f0 = xv4[0], f1 = xv4[1], f2 = xv4[2], f3 = xv4[3];
        bf16x8 v0, v1;
        v0[0] = (bf16_t)f0.x; v0[1] = (bf16_t)f0.y; v0[2] = (bf16_t)f0.z; v0[3] = (bf16_t)f0.w;
        v0[4] = (bf16_t)f1.x; v0[5] = (bf16_t)f1.y; v0[6] = (bf16_t)f1.z; v0[7] = (bf16_t)f1.w;
        v1[0] = (bf16_t)f2.x; v1[1] = (bf16_t)f2.y; v1[2] = (bf16_t)f2.z; v1[3] = (bf16_t)f2.w;
        v1[4] = (bf16_t)f3.x; v1[5] = (bf16_t)f3.y; v1[6] = (bf16_t)f3.z; v1[7] = (bf16_t)f3.w;
        *(bf16x8*)(xbr) = v0;
        *(bf16x8*)(xbr + 8) = v1;
    }

    float acc[E_NUM] = {0.f, 0.f, 0.f, 0.f, 0.f, 0.f, 0.f, 0.f};
#pragma unroll
    for (int j = 0; j < D_DIM / 64; ++j) {
        float xv = xr[lane + 64 * j];
        const float* w = wr + (size_t)(lane + 64 * j) * E_NUM;
#pragma unroll
        for (int e = 0; e < E_NUM; ++e) acc[e] += xv * w[e];
    }
#pragma unroll
    for (int off = 32; off > 0; off >>= 1) {
#pragma unroll
        for (int e = 0; e < E_NUM; ++e) acc[e] += __shfl_xor(acc[e], off, 64);
    }
    if (lane == 0) {
        float m = acc[0];
#pragma unroll
        for (int e = 1; e < E_NUM; ++e) m = fmaxf(m, acc[e]);
        float ex[E_NUM], Z = 0.f;
#pragma unroll
        for (int e = 0; e < E_NUM; ++e) { ex[e] = expf(acc[e] - m); Z += ex[e]; }
        float inv = 1.f / Z;
        int e0 = 0; float v0 = ex[0];
#pragma unroll
        for (int e = 1; e < E_NUM; ++e) if (ex[e] > v0) { v0 = ex[e]; e0 = e; }
        int e1 = -1; float v1 = -1.f;
#pragma unroll
        for (int e = 0; e < E_NUM; ++e) if (e != e0 && ex[e] > v1) { v1 = ex[e]; e1 = e; }
        float p0 = v0 * inv, p1 = v1 * inv;
        float s = p0 + p1 + 1e-20f;
        comb[t * E_NUM + e0] = p0 / s;
        comb[t * E_NUM + e1] = p1 / s;
        pairs[t] = (unsigned char)(e0 | (e1 << 4));
    }
}

// Router phase B: per-expert compaction + zero combine counters.
__global__ __launch_bounds__(256) void build_lists_kernel(
    const unsigned char* __restrict__ pairs, int* __restrict__ lists,
    int* __restrict__ counts, unsigned int* __restrict__ ctr)
{
    int e = blockIdx.x;
    int tid = threadIdx.x;
    __shared__ int cnt[256];

    // zero combine counters: 8 blocks x 256 thr x 16 = 32768
    {
        unsigned int* c = ctr + (size_t)e * 4096 + tid;
#pragma unroll
        for (int q = 0; q < 16; ++q) c[q * 256] = 0u;
    }

    const int TPT = T_TOK / 256;
    int n = 0;
#pragma unroll
    for (int q = 0; q < TPT; ++q) {
        int p = pairs[tid * TPT + q];
        if ((p & 15) == e || (p >> 4) == e) ++n;
    }
    cnt[tid] = n;
    __syncthreads();
#pragma unroll
    for (int off = 1; off < 256; off <<= 1) {
        int v = (tid >= off) ? cnt[tid - off] : 0;
        __syncthreads();
        cnt[tid] += v;
        __syncthreads();
    }
    int base = cnt[tid] - n;
    if (tid == 255) counts[e] = cnt[255];
    int* dst = lists + e * T_TOK;
#pragma unroll
    for (int q = 0; q < TPT; ++q) {
        int t = tid * TPT + q;
        int p = pairs[t];
        if ((p & 15) == e)      dst[base++] = 2 * t;
        else if ((p >> 4) == e) dst[base++] = 2 * t + 1;
    }
}

// GEMM1 (R11-proven) + appended wd-transpose blocks (bid >= NG1_BLOCKS).
__global__ __launch_bounds__(256, 2) void gemm1_kernel(
    const bf16_t* __restrict__ xbf, const bf16_t* __restrict__ wgT,
    const bf16_t* __restrict__ wuT, const int* __restrict__ lists,
    const int* __restrict__ counts, bf16_t* __restrict__ h,
    const float* __restrict__ wd, bf16_t* __restrict__ wdT)
{
    __shared__ __align__(16) bf16_t As[128 * 64];
    __shared__ __align__(16) bf16_t Bg[128 * 64];
    __shared__ __align__(16) bf16_t Bu[128 * 64];
    __shared__ int slots[128];

    int bid = blockIdx.x;
    int tid = threadIdx.x;

    if (bid >= NG1_BLOCKS) {
        int b = bid - NG1_BLOCKS;
        int nct = D_DIM / 64;            // 16
        int ct = b % nct;
        int rt = (b / nct) % (H_DIM / 64);
        int e  = b / (nct * (H_DIM / 64));
        transpose_tile(wd, wdT, H_DIM, D_DIM, e, rt, ct, tid,
                       (bf16_t(*)[65])As);
        return;
    }

    const int MT = T_TOK / 128;  // 32
    int e = bid & 7;
    int within = bid >> 3;       // 0..351
    int nt = within / MT;        // 0..10
    int mt = within - nt * MT;
    int cnt = counts[e];
    int mbase = mt * 128;
    if (mbase >= cnt) return;
    int rows = min(128, cnt - mbase);

    if (tid < 128) slots[tid] = (tid < rows) ? lists[e * T_TOK + mbase + tid] : 0;
    __syncthreads();

    int l = tid & 63, w = tid >> 6;
    int rbase = w * 32 + (l >> 3);            // staged row (q=0)
    int sc = ((l & 7) ^ (l >> 3)) * 8;        // pre-swizzled source chunk

    const bf16_t* gA0 = xbf + (size_t)(slots[rbase] >> 1) * D_DIM + sc;
    const bf16_t* gA1 = xbf + (size_t)(slots[rbase + 8] >> 1) * D_DIM + sc;
    const bf16_t* gA2 = xbf + (size_t)(slots[rbase + 16] >> 1) * D_DIM + sc;
    const bf16_t* gA3 = xbf + (size_t)(slots[rbase + 24] >> 1) * D_DIM + sc;
    const bf16_t* gB = wgT + ((size_t)e * H_DIM + nt * 128 + rbase) * D_DIM + sc;
    const bf16_t* gU = wuT + ((size_t)e * H_DIM + nt * 128 + rbase) * D_DIM + sc;
    bf16_t* lA = As + w * 2048 + l * 8;       // linear dest
    bf16_t* lG = Bg + w * 2048 + l * 8;
    bf16_t* lU = Bu + w * 2048 + l * 8;

    int wm = (w >> 1) * 64, wn = (w & 1) * 64;
    int lr = l & 15, lq = l >> 4;

    f32x4 accg[4][4], accu[4][4];
#pragma unroll
    for (int i = 0; i < 4; ++i)
#pragma unroll
        for (int j = 0; j < 4; ++j) {
            accg[i][j] = (f32x4){0.f, 0.f, 0.f, 0.f};
            accu[i][j] = (f32x4){0.f, 0.f, 0.f, 0.f};
        }

    for (int kt = 0; kt < D_DIM; kt += 64) {
        gload16(gA0 + kt, lA);
        gload16(gA1 + kt, lA + 512);
        gload16(gA2 + kt, lA + 1024);
        gload16(gA3 + kt, lA + 1536);
        gload16(gB + kt, lG);
        gload16(gB + (size_t)8 * D_DIM + kt, lG + 512);
        gload16(gB + (size_t)16 * D_DIM + kt, lG + 1024);
        gload16(gB + (size_t)24 * D_DIM + kt, lG + 1536);
        gload16(gU + kt, lU);
        gload16(gU + (size_t)8 * D_DIM + kt, lU + 512);
        gload16(gU + (size_t)16 * D_DIM + kt, lU + 1024);
        gload16(gU + (size_t)24 * D_DIM + kt, lU + 1536);
        __syncthreads();

#pragma unroll
        for (int ks = 0; ks < 2; ++ks) {
            int ch = (((ks * 4 + lq) ^ (lr & 7))) * 8;
            bf16x8 af[4], bg[4], bu[4];
#pragma unroll
            for (int i = 0; i < 4; ++i)
                af[i] = *(const bf16x8*)(As + (wm + i * 16 + lr) * 64 + ch);
#pragma unroll
            for (int j = 0; j < 4; ++j) {
                bg[j] = *(const bf16x8*)(Bg + (wn + j * 16 + lr) * 64 + ch);
                bu[j] = *(const bf16x8*)(Bu + (wn + j * 16 + lr) * 64 + ch);
            }
#pragma unroll
            for (int i = 0; i < 4; ++i)
#pragma unroll
                for (int j = 0; j < 4; ++j) {
                    accg[i][j] = __builtin_amdgcn_mfma_f32_16x16x32_bf16(af[i], bg[j], accg[i][j], 0, 0, 0);
                    accu[i][j] = __builtin_amdgcn_mfma_f32_16x16x32_bf16(af[i], bu[j], accu[i][j], 0, 0, 0);
                }
        }
        __syncthreads();
    }

#pragma unroll
    for (int i = 0; i < 4; ++i) {
#pragma unroll
        for (int jj = 0; jj < 4; ++jj) {
            int row = wm + i * 16 + lq * 4 + jj;
            if (row < rows) {
                int slot = slots[row];
                bf16_t* hrow = h + (size_t)slot * H_DIM + (size_t)nt * 128 + wn;
#pragma unroll
                for (int j = 0; j < 4; ++j) {
                    float g = accg[i][j][jj];
                    float u = accu[i][j][jj];
                    float val = (g / (1.f + __expf(-g))) * u;
                    hrow[j * 16 + lr] = (bf16_t)val;
                }
            }
        }
    }
}

// GEMM2 + last-writer combine: contrib[slot] = (h[slot] @ Wd[e]) * weight;
// second block to finish a (token, nt) pair combines it into f32 out.
__global__ __launch_bounds__(256, 2) void gemm2_kernel(
    const bf16_t* __restrict__ h, const bf16_t* __restrict__ wdT,
    const int* __restrict__ lists, const int* __restrict__ counts,
    const float* __restrict__ comb, bf16_t* __restrict__ contrib,
    float* __restrict__ out, unsigned int* __restrict__ ctr)
{
    const int MT = T_TOK / 128;  // 32
    int bid = blockIdx.x;
    int e = bid & 7;
    int within = bid >> 3;       // 0..255
    int nt = within / MT;        // 0..7
    int mt = within - nt * MT;
    int cnt = counts[e];
    int mbase = mt * 128;
    if (mbase >= cnt) return;
    int rows = min(128, cnt - mbase);

    __shared__ __align__(16) bf16_t As[128 * 64];
    __shared__ __align__(16) bf16_t Bs[128 * 64];
    __shared__ int slots[128];

    int tid = threadIdx.x;
    if (tid < 128) slots[tid] = (tid < rows) ? lists[e * T_TOK + mbase + tid] : 0;
    __syncthreads();

    int l = tid & 63, w = tid >> 6;
    int rbase = w * 32 + (l >> 3);
    int sc = ((l & 7) ^ (l >> 3)) * 8;

    const bf16_t* gA0 = h + (size_t)slots[rbase] * H_DIM + sc;
    const bf16_t* gA1 = h + (size_t)slots[rbase + 8] * H_DIM + sc;
    const bf16_t* gA2 = h + (size_t)slots[rbase + 16] * H_DIM + sc;
    const bf16_t* gA3 = h + (size_t)slots[rbase + 24] * H_DIM + sc;
    const bf16_t* gB = wdT + ((size_t)e * D_DIM + nt * 128 + rbase) * H_DIM + sc;
    bf16_t* lA = As + w * 2048 + l * 8;
    bf16_t* lB = Bs + w * 2048 + l * 8;

    int wm = (w >> 1) * 64, wn = (w & 1) * 64;
    int lr = l & 15, lq = l >> 4;

    f32x4 acc[4][4];
#pragma unroll
    for (int i = 0; i < 4; ++i)
#pragma unroll
        for (int j = 0; j < 4; ++j) acc[i][j] = (f32x4){0.f, 0.f, 0.f, 0.f};

    for (int kt = 0; kt < H_DIM; kt += 64) {
        gload16(gA0 + kt, lA);
        gload16(gA1 + kt, lA + 512);
        gload16(gA2 + kt, lA + 1024);
        gload16(gA3 + kt, lA + 1536);
        gload16(gB + kt, lB);
        gload16(gB + (size_t)8 * H_DIM + kt, lB + 512);
        gload16(gB + (size_t)16 * H_DIM + kt, lB + 1024);
        gload16(gB + (size_t)24 * H_DIM + kt, lB + 1536);
        __syncthreads();

#pragma unroll
        for (int ks = 0; ks < 2; ++ks) {
            int ch = (((ks * 4 + lq) ^ (lr & 7))) * 8;
            bf16x8 af[4], bf[4];
#pragma unroll
            for (int i = 0; i < 4; ++i)
                af[i] = *(const bf16x8*)(As + (wm + i * 16 + lr) * 64 + ch);
#pragma unroll
            for (int j = 0; j < 4; ++j)
                bf[j] = *(const bf16x8*)(Bs + (wn + j * 16 + lr) * 64 + ch);
#pragma unroll
            for (int i = 0; i < 4; ++i)
#pragma unroll
                for (int j = 0; j < 4; ++j)
                    acc[i][j] = __builtin_amdgcn_mfma_f32_16x16x32_bf16(af[i], bf[j], acc[i][j], 0, 0, 0);
        }
        __syncthreads();
    }

#pragma unroll
    for (int i = 0; i < 4; ++i) {
#pragma unroll
        for (int jj = 0; jj < 4; ++jj) {
            int row = wm + i * 16 + lq * 4 + jj;
            if (row < rows) {
                int slot = slots[row];
                float wgt = comb[(slot >> 1) * E_NUM + e];
                bf16_t* crow = contrib + (size_t)slot * D_DIM + (size_t)nt * 128 + wn;
#pragma unroll
                for (int j = 0; j < 4; ++j)
                    crow[j * 16 + lr] = (bf16_t)(acc[i][j][jj] * wgt);
            }
        }
    }

    // ---- last-writer combine (threadfence-reduction pattern) ----
    __threadfence();      // release this block's contrib stores (device scope)
    __syncthreads();      // all threads' stores done + fenced
    if (tid < rows) {
        int slot = slots[tid];
        int t = slot >> 1;
        unsigned old = atomicAdd(&ctr[t * 8 + nt], 1u);
        if (old == 1u) {  // second arriver: both slots' tiles complete
            __threadfence();  // acquire the other block's stores
            const bf16_t* ca = contrib + (size_t)(2 * t) * D_DIM + nt * 128;
            const bf16_t* cb = contrib + (size_t)(2 * t + 1) * D_DIM + nt * 128;
            float* orow = out + (size_t)t * D_DIM + nt * 128;
#pragma unroll
            for (int c0 = 0; c0 < 128; c0 += 8) {
                bf16x8 a = *(const bf16x8*)(ca + c0);
                bf16x8 b = *(const bf16x8*)(cb + c0);
                float4 r0, r1;
                r0.x = (float)a[0] + (float)b[0];
                r0.y = (float)a[1] + (float)b[1];
                r0.z = (float)a[2] + (float)b[2];
                r0.w = (float)a[3] + (float)b[3];
                r1.x = (float)a[4] + (float)b[4];
                r1.y = (float)a[5] + (float)b[5];
                r1.z = (float)a[6] + (float)b[6];
                r1.w = (float)a[7] + (float)b[7];
                *(float4*)(orow + c0) = r0;
                *(float4*)(orow + c0 + 4) = r1;
            }
        }
    }
}

extern "C" void kernel_launch(void* const* d_in, const int* in_sizes, int n_in,
                              void* d_out, int out_size, void* d_ws, size_t ws_size,
                              hipStream_t stream)
{
    const float* x  = (const float*)d_in[0];
    const float* wr = (const float*)d_in[1];
    const float* wg = (const float*)d_in[2];
    const float* wu = (const float*)d_in[3];
    const float* wd = (const float*)d_in[4];
    float* out = (float*)d_out;

    char* ws = (char*)d_ws;
    int*    counts  = (int*)(ws + OFF_COUNTS);
    float*  comb    = (float*)(ws + OFF_COMB);
    int*    lists   = (int*)(ws + OFF_LISTS);
    unsigned char* pairs = (unsigned char*)(ws + OFF_PAIRS);
    bf16_t* xbf     = (bf16_t*)(ws + OFF_XBF);
    bf16_t* wgT     = (bf16_t*)(ws + OFF_WGT);
    bf16_t* wuT     = (bf16_t*)(ws + OFF_WUT);
    bf16_t* wdT     = (bf16_t*)(ws + OFF_WDT);
    bf16_t* h       = (bf16_t*)(ws + OFF_H);
    bf16_t* contrib = (bf16_t*)(ws + OFF_CONTRIB);
    unsigned int* ctr = (unsigned int*)(ws + OFF_CTR);

    prep_kernel<<<dim3(NTRANS_BLOCKS + NROUTER_BLOCKS), dim3(256), 0, stream>>>(
        wg, wu, wgT, wuT, x, wr, xbf, comb, pairs);
    build_lists_kernel<<<dim3(E_NUM), dim3(256), 0, stream>>>(pairs, lists, counts, ctr);
    gemm1_kernel<<<dim3(NG1_BLOCKS + NWD_BLOCKS), dim3(256), 0, stream>>>(
        xbf, wgT, wuT, lists, counts, h, wd, wdT);
    gemm2_kernel<<<dim3(E_NUM * (T_TOK / 128) * (D_DIM / 128)), dim3(256), 0, stream>>>(
        h, wdT, lists, counts, comb, contrib, out, ctr);
}

// Round 19
// 174.057 us; speedup vs baseline: 1.7790x; 1.7790x over previous
//
#include <hip/hip_runtime.h>
#include <hip/hip_bf16.h>

// MoE FFN: T=4096 tokens, D=1024, E=8, H=1408, top-2.
// R19 = R17 restored exactly (measured best, 174.7us).
// - prep: wg/wu transpose+convert + router in one launch.
// - build_lists: per-expert LDS-scan compaction (deterministic).
// - gemm1: 128x128/BK=64/XOR-swizzle/sbuf/gload_lds + appended wd-transpose
//   blocks filling the pinned-schedule tail (R17 win, -6us).
// - gemm2: same template; separate combine kernel.
// Falsified: combine fusion via atomics (R15, -15us) and via last-writer
// fence pattern (R18, -135us: epilogue flipped regalloc to 64 VGPR -> spill).

#define T_TOK 4096
#define D_DIM 1024
#define E_NUM 8
#define H_DIM 1408

typedef __bf16 bf16_t;
typedef __bf16 bf16x8 __attribute__((ext_vector_type(8)));
typedef float f32x4 __attribute__((ext_vector_type(4)));

// ---- workspace layout (bytes) ----
#define OFF_COUNTS   0
#define OFF_COMB     256                                   // T*E*4 = 131072
#define OFF_LISTS    (OFF_COMB + T_TOK*E_NUM*4)            // E*T*4 = 131072
#define OFF_PAIRS    (OFF_LISTS + E_NUM*T_TOK*4)           // T bytes
#define OFF_XBF      (OFF_PAIRS + T_TOK)                   // T*D*2
#define OFF_WGT      (OFF_XBF + (size_t)T_TOK*D_DIM*2)     // E*H*D*2 each
#define OFF_WUT      (OFF_WGT + (size_t)E_NUM*H_DIM*D_DIM*2)
#define OFF_WDT      (OFF_WUT + (size_t)E_NUM*H_DIM*D_DIM*2)
#define OFF_H        (OFF_WDT + (size_t)E_NUM*H_DIM*D_DIM*2)
#define OFF_CONTRIB  (OFF_H + (size_t)2*T_TOK*H_DIM*2)
// total ~117.7 MB

#define NTRANS_BLOCKS 5632   // wg + wu only (wd transpose moved to gemm1 grid)
#define NROUTER_BLOCKS (T_TOK / 4)
#define NG1_BLOCKS (E_NUM * (T_TOK / 128) * (H_DIM / 128))  // 2816
#define NWD_BLOCKS 2816       // (D/64) x (H/64) x E

__device__ __forceinline__ void gload16(const bf16_t* g, bf16_t* l) {
    __builtin_amdgcn_global_load_lds(
        (const __attribute__((address_space(1))) void*)g,
        (__attribute__((address_space(3))) void*)l,
        16, 0, 0);
}

// Shared transpose body: in [R][C] fp32 tile (rt,ct) of expert e -> out [C][R] bf16.
__device__ __forceinline__ void transpose_tile(
    const float* __restrict__ in, bf16_t* __restrict__ out, int R, int C,
    int e, int rt, int ct, int tid, bf16_t (*tile)[65])
{
    int r = tid >> 2, c0 = (tid & 3) * 16;
    const float* src = in + ((size_t)e * R + rt * 64) * C + (size_t)ct * 64;
#pragma unroll
    for (int q = 0; q < 4; ++q) {
        float4 f = *(const float4*)(src + (size_t)r * C + c0 + q * 4);
        tile[c0 + q * 4 + 0][r] = (bf16_t)f.x;
        tile[c0 + q * 4 + 1][r] = (bf16_t)f.y;
        tile[c0 + q * 4 + 2][r] = (bf16_t)f.z;
        tile[c0 + q * 4 + 3][r] = (bf16_t)f.w;
    }
    __syncthreads();
    bf16_t* dst = out + ((size_t)e * C + ct * 64) * R + (size_t)rt * 64;
    int cc = tid >> 2, rr0 = (tid & 3) * 16;
    bf16x8 v0, v1;
#pragma unroll
    for (int q = 0; q < 8; ++q) { v0[q] = tile[cc][rr0 + q]; v1[q] = tile[cc][rr0 + 8 + q]; }
    *(bf16x8*)(dst + (size_t)cc * R + rr0) = v0;
    *(bf16x8*)(dst + (size_t)cc * R + rr0 + 8) = v1;
}

// Fused pre-pass: wg/wu transpose+convert (blocks [0,5632)) + router (rest).
__global__ __launch_bounds__(256) void prep_kernel(
    const float* __restrict__ wg, const float* __restrict__ wu,
    bf16_t* __restrict__ wgT, bf16_t* __restrict__ wuT,
    const float* __restrict__ x, const float* __restrict__ wr,
    bf16_t* __restrict__ xbf, float* __restrict__ comb,
    unsigned char* __restrict__ pairs)
{
    int bid = blockIdx.x;
    int tid = threadIdx.x;

    if (bid < NTRANS_BLOCKS) {
        __shared__ bf16_t tile[64][65];
        const float* in; bf16_t* out;
        if (bid < 2816)      { in = wg; out = wgT; }
        else                 { in = wu; out = wuT; bid -= 2816; }
        int nct = H_DIM / 64;            // 22
        int ct = bid % nct;
        int rt = (bid / nct) % (D_DIM / 64);
        int e  = bid / (nct * (D_DIM / 64));
        transpose_tile(in, out, D_DIM, H_DIM, e, rt, ct, tid, tile);
        return;
    }

    // ---- router ----
    int widx = tid >> 6;
    int lane = tid & 63;
    int t = (bid - NTRANS_BLOCKS) * 4 + widx;
    const float* xr = x + (size_t)t * D_DIM;

    {
        const float4* xv4 = (const float4*)(xr + lane * 16);
        bf16_t* xbr = xbf + (size_t)t * D_DIM + lane * 16;
        float4 f0 = xv4[0], f1 = xv4[1], f2 = xv4[2], f3 = xv4[3];
        bf16x8 v0, v1;
        v0[0] = (bf16_t)f0.x; v0[1] = (bf16_t)f0.y; v0[2] = (bf16_t)f0.z; v0[3] = (bf16_t)f0.w;
        v0[4] = (bf16_t)f1.x; v0[5] = (bf16_t)f1.y; v0[6] = (bf16_t)f1.z; v0[7] = (bf16_t)f1.w;
        v1[0] = (bf16_t)f2.x; v1[1] = (bf16_t)f2.y; v1[2] = (bf16_t)f2.z; v1[3] = (bf16_t)f2.w;
        v1[4] = (bf16_t)f3.x; v1[5] = (bf16_t)f3.y; v1[6] = (bf16_t)f3.z; v1[7] = (bf16_t)f3.w;
        *(bf16x8*)(xbr) = v0;
        *(bf16x8*)(xbr + 8) = v1;
    }

    float acc[E_NUM] = {0.f, 0.f, 0.f, 0.f, 0.f, 0.f, 0.f, 0.f};
#pragma unroll
    for (int j = 0; j < D_DIM / 64; ++j) {
        float xv = xr[lane + 64 * j];
        const float* w = wr + (size_t)(lane + 64 * j) * E_NUM;
#pragma unroll
        for (int e = 0; e < E_NUM; ++e) acc[e] += xv * w[e];
    }
#pragma unroll
    for (int off = 32; off > 0; off >>= 1) {
#pragma unroll
        for (int e = 0; e < E_NUM; ++e) acc[e] += __shfl_xor(acc[e], off, 64);
    }
    if (lane == 0) {
        float m = acc[0];
#pragma unroll
        for (int e = 1; e < E_NUM; ++e) m = fmaxf(m, acc[e]);
        float ex[E_NUM], Z = 0.f;
#pragma unroll
        for (int e = 0; e < E_NUM; ++e) { ex[e] = expf(acc[e] - m); Z += ex[e]; }
        float inv = 1.f / Z;
        int e0 = 0; float v0 = ex[0];
#pragma unroll
        for (int e = 1; e < E_NUM; ++e) if (ex[e] > v0) { v0 = ex[e]; e0 = e; }
        int e1 = -1; float v1 = -1.f;
#pragma unroll
        for (int e = 0; e < E_NUM; ++e) if (e != e0 && ex[e] > v1) { v1 = ex[e]; e1 = e; }
        float p0 = v0 * inv, p1 = v1 * inv;
        float s = p0 + p1 + 1e-20f;
        comb[t * E_NUM + e0] = p0 / s;
        comb[t * E_NUM + e1] = p1 / s;
        pairs[t] = (unsigned char)(e0 | (e1 << 4));
    }
}

// Router phase B: one block per expert, LDS-scan compaction. Deterministic.
__global__ __launch_bounds__(256) void build_lists_kernel(
    const unsigned char* __restrict__ pairs, int* __restrict__ lists,
    int* __restrict__ counts)
{
    int e = blockIdx.x;
    int tid = threadIdx.x;
    __shared__ int cnt[256];

    const int TPT = T_TOK / 256;
    int n = 0;
#pragma unroll
    for (int q = 0; q < TPT; ++q) {
        int p = pairs[tid * TPT + q];
        if ((p & 15) == e || (p >> 4) == e) ++n;
    }
    cnt[tid] = n;
    __syncthreads();
#pragma unroll
    for (int off = 1; off < 256; off <<= 1) {
        int v = (tid >= off) ? cnt[tid - off] : 0;
        __syncthreads();
        cnt[tid] += v;
        __syncthreads();
    }
    int base = cnt[tid] - n;
    if (tid == 255) counts[e] = cnt[255];
    int* dst = lists + e * T_TOK;
#pragma unroll
    for (int q = 0; q < TPT; ++q) {
        int t = tid * TPT + q;
        int p = pairs[t];
        if ((p & 15) == e)      dst[base++] = 2 * t;
        else if ((p >> 4) == e) dst[base++] = 2 * t + 1;
    }
}

// GEMM1 (R11-proven) + appended wd-transpose blocks (bid >= NG1_BLOCKS).
// Transpose tile aliases As (8.3KB <= 16KB) -> LDS stays 49.6KB.
__global__ __launch_bounds__(256, 2) void gemm1_kernel(
    const bf16_t* __restrict__ xbf, const bf16_t* __restrict__ wgT,
    const bf16_t* __restrict__ wuT, const int* __restrict__ lists,
    const int* __restrict__ counts, bf16_t* __restrict__ h,
    const float* __restrict__ wd, bf16_t* __restrict__ wdT)
{
    __shared__ __align__(16) bf16_t As[128 * 64];
    __shared__ __align__(16) bf16_t Bg[128 * 64];
    __shared__ __align__(16) bf16_t Bu[128 * 64];
    __shared__ int slots[128];

    int bid = blockIdx.x;
    int tid = threadIdx.x;

    if (bid >= NG1_BLOCKS) {
        // wd: [E][H][D] fp32 -> wdT [E][D][H] bf16 (consumed by gemm2 only)
        int b = bid - NG1_BLOCKS;
        int nct = D_DIM / 64;            // 16
        int ct = b % nct;
        int rt = (b / nct) % (H_DIM / 64);
        int e  = b / (nct * (H_DIM / 64));
        transpose_tile(wd, wdT, H_DIM, D_DIM, e, rt, ct, tid,
                       (bf16_t(*)[65])As);
        return;
    }

    const int MT = T_TOK / 128;  // 32
    int e = bid & 7;
    int within = bid >> 3;       // 0..351
    int nt = within / MT;        // 0..10
    int mt = within - nt * MT;
    int cnt = counts[e];
    int mbase = mt * 128;
    if (mbase >= cnt) return;
    int rows = min(128, cnt - mbase);

    if (tid < 128) slots[tid] = (tid < rows) ? lists[e * T_TOK + mbase + tid] : 0;
    __syncthreads();

    int l = tid & 63, w = tid >> 6;
    int rbase = w * 32 + (l >> 3);            // staged row (q=0)
    int sc = ((l & 7) ^ (l >> 3)) * 8;        // pre-swizzled source chunk

    const bf16_t* gA0 = xbf + (size_t)(slots[rbase] >> 1) * D_DIM + sc;
    const bf16_t* gA1 = xbf + (size_t)(slots[rbase + 8] >> 1) * D_DIM + sc;
    const bf16_t* gA2 = xbf + (size_t)(slots[rbase + 16] >> 1) * D_DIM + sc;
    const bf16_t* gA3 = xbf + (size_t)(slots[rbase + 24] >> 1) * D_DIM + sc;
    const bf16_t* gB = wgT + ((size_t)e * H_DIM + nt * 128 + rbase) * D_DIM + sc;
    const bf16_t* gU = wuT + ((size_t)e * H_DIM + nt * 128 + rbase) * D_DIM + sc;
    bf16_t* lA = As + w * 2048 + l * 8;       // linear dest
    bf16_t* lG = Bg + w * 2048 + l * 8;
    bf16_t* lU = Bu + w * 2048 + l * 8;

    int wm = (w >> 1) * 64, wn = (w & 1) * 64;
    int lr = l & 15, lq = l >> 4;

    f32x4 accg[4][4], accu[4][4];
#pragma unroll
    for (int i = 0; i < 4; ++i)
#pragma unroll
        for (int j = 0; j < 4; ++j) {
            accg[i][j] = (f32x4){0.f, 0.f, 0.f, 0.f};
            accu[i][j] = (f32x4){0.f, 0.f, 0.f, 0.f};
        }

    for (int kt = 0; kt < D_DIM; kt += 64) {
        gload16(gA0 + kt, lA);
        gload16(gA1 + kt, lA + 512);
        gload16(gA2 + kt, lA + 1024);
        gload16(gA3 + kt, lA + 1536);
        gload16(gB + kt, lG);
        gload16(gB + (size_t)8 * D_DIM + kt, lG + 512);
        gload16(gB + (size_t)16 * D_DIM + kt, lG + 1024);
        gload16(gB + (size_t)24 * D_DIM + kt, lG + 1536);
        gload16(gU + kt, lU);
        gload16(gU + (size_t)8 * D_DIM + kt, lU + 512);
        gload16(gU + (size_t)16 * D_DIM + kt, lU + 1024);
        gload16(gU + (size_t)24 * D_DIM + kt, lU + 1536);
        __syncthreads();

#pragma unroll
        for (int ks = 0; ks < 2; ++ks) {
            int ch = (((ks * 4 + lq) ^ (lr & 7))) * 8;
            bf16x8 af[4], bg[4], bu[4];
#pragma unroll
            for (int i = 0; i < 4; ++i)
                af[i] = *(const bf16x8*)(As + (wm + i * 16 + lr) * 64 + ch);
#pragma unroll
            for (int j = 0; j < 4; ++j) {
                bg[j] = *(const bf16x8*)(Bg + (wn + j * 16 + lr) * 64 + ch);
                bu[j] = *(const bf16x8*)(Bu + (wn + j * 16 + lr) * 64 + ch);
            }
#pragma unroll
            for (int i = 0; i < 4; ++i)
#pragma unroll
                for (int j = 0; j < 4; ++j) {
                    accg[i][j] = __builtin_amdgcn_mfma_f32_16x16x32_bf16(af[i], bg[j], accg[i][j], 0, 0, 0);
                    accu[i][j] = __builtin_amdgcn_mfma_f32_16x16x32_bf16(af[i], bu[j], accu[i][j], 0, 0, 0);
                }
        }
        __syncthreads();
    }

#pragma unroll
    for (int i = 0; i < 4; ++i) {
#pragma unroll
        for (int jj = 0; jj < 4; ++jj) {
            int row = wm + i * 16 + lq * 4 + jj;
            if (row < rows) {
                int slot = slots[row];
                bf16_t* hrow = h + (size_t)slot * H_DIM + (size_t)nt * 128 + wn;
#pragma unroll
                for (int j = 0; j < 4; ++j) {
                    float g = accg[i][j][jj];
                    float u = accu[i][j][jj];
                    float val = (g / (1.f + __expf(-g))) * u;
                    hrow[j * 16 + lr] = (bf16_t)val;
                }
            }
        }
    }
}

// GEMM2 (R11-proven): contrib[slot] = (h[slot] @ Wd[e]) * comb_weight.
__global__ __launch_bounds__(256, 2) void gemm2_kernel(
    const bf16_t* __restrict__ h, const bf16_t* __restrict__ wdT,
    const int* __restrict__ lists, const int* __restrict__ counts,
    const float* __restrict__ comb, bf16_t* __restrict__ contrib)
{
    const int MT = T_TOK / 128;  // 32
    int bid = blockIdx.x;
    int e = bid & 7;
    int within = bid >> 3;       // 0..255
    int nt = within / MT;        // 0..7
    int mt = within - nt * MT;
    int cnt = counts[e];
    int mbase = mt * 128;
    if (mbase >= cnt) return;
    int rows = min(128, cnt - mbase);

    __shared__ __align__(16) bf16_t As[128 * 64];
    __shared__ __align__(16) bf16_t Bs[128 * 64];
    __shared__ int slots[128];

    int tid = threadIdx.x;
    if (tid < 128) slots[tid] = (tid < rows) ? lists[e * T_TOK + mbase + tid] : 0;
    __syncthreads();

    int l = tid & 63, w = tid >> 6;
    int rbase = w * 32 + (l >> 3);
    int sc = ((l & 7) ^ (l >> 3)) * 8;

    const bf16_t* gA0 = h + (size_t)slots[rbase] * H_DIM + sc;
    const bf16_t* gA1 = h + (size_t)slots[rbase + 8] * H_DIM + sc;
    const bf16_t* gA2 = h + (size_t)slots[rbase + 16] * H_DIM + sc;
    const bf16_t* gA3 = h + (size_t)slots[rbase + 24] * H_DIM + sc;
    const bf16_t* gB = wdT + ((size_t)e * D_DIM + nt * 128 + rbase) * H_DIM + sc;
    bf16_t* lA = As + w * 2048 + l * 8;
    bf16_t* lB = Bs + w * 2048 + l * 8;

    int wm = (w >> 1) * 64, wn = (w & 1) * 64;
    int lr = l & 15, lq = l >> 4;

    f32x4 acc[4][4];
#pragma unroll
    for (int i = 0; i < 4; ++i)
#pragma unroll
        for (int j = 0; j < 4; ++j) acc[i][j] = (f32x4){0.f, 0.f, 0.f, 0.f};

    for (int kt = 0; kt < H_DIM; kt += 64) {
        gload16(gA0 + kt, lA);
        gload16(gA1 + kt, lA + 512);
        gload16(gA2 + kt, lA + 1024);
        gload16(gA3 + kt, lA + 1536);
        gload16(gB + kt, lB);
        gload16(gB + (size_t)8 * H_DIM + kt, lB + 512);
        gload16(gB + (size_t)16 * H_DIM + kt, lB + 1024);
        gload16(gB + (size_t)24 * H_DIM + kt, lB + 1536);
        __syncthreads();

#pragma unroll
        for (int ks = 0; ks < 2; ++ks) {
            int ch = (((ks * 4 + lq) ^ (lr & 7))) * 8;
            bf16x8 af[4], bf[4];
#pragma unroll
            for (int i = 0; i < 4; ++i)
                af[i] = *(const bf16x8*)(As + (wm + i * 16 + lr) * 64 + ch);
#pragma unroll
            for (int j = 0; j < 4; ++j)
                bf[j] = *(const bf16x8*)(Bs + (wn + j * 16 + lr) * 64 + ch);
#pragma unroll
            for (int i = 0; i < 4; ++i)
#pragma unroll
                for (int j = 0; j < 4; ++j)
                    acc[i][j] = __builtin_amdgcn_mfma_f32_16x16x32_bf16(af[i], bf[j], acc[i][j], 0, 0, 0);
        }
        __syncthreads();
    }

#pragma unroll
    for (int i = 0; i < 4; ++i) {
#pragma unroll
        for (int jj = 0; jj < 4; ++jj) {
            int row = wm + i * 16 + lq * 4 + jj;
            if (row < rows) {
                int slot = slots[row];
                float wgt = comb[(slot >> 1) * E_NUM + e];
                bf16_t* crow = contrib + (size_t)slot * D_DIM + (size_t)nt * 128 + wn;
#pragma unroll
                for (int j = 0; j < 4; ++j)
                    crow[j * 16 + lr] = (bf16_t)(acc[i][j][jj] * wgt);
            }
        }
    }
}

// out[t][d] = contrib[2t][d] + contrib[2t+1][d]
__global__ __launch_bounds__(256) void combine_kernel(
    const bf16_t* __restrict__ contrib, float* __restrict__ out)
{
    int idx = blockIdx.x * 256 + threadIdx.x;
    int t = idx >> 7;
    int d = (idx & 127) * 8;
    bf16x8 a = *(const bf16x8*)(contrib + (size_t)(2 * t) * D_DIM + d);
    bf16x8 b = *(const bf16x8*)(contrib + (size_t)(2 * t + 1) * D_DIM + d);
    float4 r0, r1;
    r0.x = (float)a[0] + (float)b[0];
    r0.y = (float)a[1] + (float)b[1];
    r0.z = (float)a[2] + (float)b[2];
    r0.w = (float)a[3] + (float)b[3];
    r1.x = (float)a[4] + (float)b[4];
    r1.y = (float)a[5] + (float)b[5];
    r1.z = (float)a[6] + (float)b[6];
    r1.w = (float)a[7] + (float)b[7];
    *(float4*)(out + (size_t)t * D_DIM + d) = r0;
    *(float4*)(out + (size_t)t * D_DIM + d + 4) = r1;
}

extern "C" void kernel_launch(void* const* d_in, const int* in_sizes, int n_in,
                              void* d_out, int out_size, void* d_ws, size_t ws_size,
                              hipStream_t stream)
{
    const float* x  = (const float*)d_in[0];
    const float* wr = (const float*)d_in[1];
    const float* wg = (const float*)d_in[2];
    const float* wu = (const float*)d_in[3];
    const float* wd = (const float*)d_in[4];
    float* out = (float*)d_out;

    char* ws = (char*)d_ws;
    int*    counts  = (int*)(ws + OFF_COUNTS);
    float*  comb    = (float*)(ws + OFF_COMB);
    int*    lists   = (int*)(ws + OFF_LISTS);
    unsigned char* pairs = (unsigned char*)(ws + OFF_PAIRS);
    bf16_t* xbf     = (bf16_t*)(ws + OFF_XBF);
    bf16_t* wgT     = (bf16_t*)(ws + OFF_WGT);
    bf16_t* wuT     = (bf16_t*)(ws + OFF_WUT);
    bf16_t* wdT     = (bf16_t*)(ws + OFF_WDT);
    bf16_t* h       = (bf16_t*)(ws + OFF_H);
    bf16_t* contrib = (bf16_t*)(ws + OFF_CONTRIB);

    prep_kernel<<<dim3(NTRANS_BLOCKS + NROUTER_BLOCKS), dim3(256), 0, stream>>>(
        wg, wu, wgT, wuT, x, wr, xbf, comb, pairs);
    build_lists_kernel<<<dim3(E_NUM), dim3(256), 0, stream>>>(pairs, lists, counts);
    gemm1_kernel<<<dim3(NG1_BLOCKS + NWD_BLOCKS), dim3(256), 0, stream>>>(
        xbf, wgT, wuT, lists, counts, h, wd, wdT);
    gemm2_kernel<<<dim3(E_NUM * (T_TOK / 128) * (D_DIM / 128)), dim3(256), 0, stream>>>(
        h, wdT, lists, counts, comb, contrib);
    combine_kernel<<<dim3(T_TOK * D_DIM / 8 / 256), dim3(256), 0, stream>>>(contrib, out);
}